// Round 1
// baseline (458.509 us; speedup 1.0000x reference)
//
#include <hip/hip_runtime.h>
#include <hip/hip_bf16.h>
#include <stdint.h>

// Problem constants (B=2, T=2048, D=1024, F=4096, E=8)
#define N_TOK 4096      // B*T
#define D_DIM 1024
#define F_DIM 4096
#define E_NUM 8

typedef unsigned short u16;
typedef __attribute__((ext_vector_type(8))) short short8;   // 8 bf16 (4 VGPRs)
typedef __attribute__((ext_vector_type(4))) float f32x4;

__device__ __forceinline__ u16 f2bf(float f) {
  union { float f; uint32_t u; } v; v.f = f;
  uint32_t u = v.u;
  uint32_t r = (u + 0x7FFFu + ((u >> 16) & 1u)) >> 16;
  return (u16)r;
}

__device__ __forceinline__ void gld_lds16(const u16* g, u16* l) {
  // async global->LDS, 16B per lane; LDS dest = wave-uniform base + lane*16
  __builtin_amdgcn_global_load_lds(
      (const __attribute__((address_space(1))) uint32_t*)g,
      (__attribute__((address_space(3))) uint32_t*)l, 16, 0, 0);
}

// ---------------- convert x (fp32 -> bf16) ----------------
__global__ void cvt_x_kernel(const float* __restrict__ x, u16* __restrict__ xb, int n4) {
  int i = blockIdx.x * blockDim.x + threadIdx.x;
  if (i < n4) {
    float4 v = ((const float4*)x)[i];
    ushort4 o;
    o.x = f2bf(v.x); o.y = f2bf(v.y); o.z = f2bf(v.z); o.w = f2bf(v.w);
    ((ushort4*)xb)[i] = o;
  }
}

// ---------- transpose+convert: in [E][R][C] f32 -> out [E][C][R] bf16 ----------
__global__ void transpose_cvt_kernel(const float* __restrict__ in, u16* __restrict__ out,
                                     int R, int C) {
  __shared__ u16 tile[32][33];
  int e = blockIdx.z;
  int c0 = blockIdx.x * 32, r0 = blockIdx.y * 32;
  const float* src = in + (size_t)e * R * C;
  u16* dst = out + (size_t)e * R * C;
  int tx = threadIdx.x, ty = threadIdx.y;  // (32, 8)
#pragma unroll
  for (int i = 0; i < 4; ++i) {
    int r = r0 + ty + i * 8;
    tile[ty + i * 8][tx] = f2bf(src[(size_t)r * C + c0 + tx]);
  }
  __syncthreads();
#pragma unroll
  for (int i = 0; i < 4; ++i) {
    int c = c0 + ty + i * 8;
    dst[(size_t)c * R + r0 + tx] = tile[tx][ty + i * 8];
  }
}

// ---------------- gate: logits, top-2, softmax, routing ----------------
__global__ void gate_kernel(const float* __restrict__ x, const float* __restrict__ Wg,
                            int* __restrict__ cnt, int* __restrict__ tok_list,
                            float* __restrict__ sc2) {
  int n = blockIdx.x;
  int l = threadIdx.x;  // 64
  const float* xr = x + (size_t)n * D_DIM;
  float acc[E_NUM];
#pragma unroll
  for (int e = 0; e < E_NUM; ++e) acc[e] = 0.f;
  for (int d = l; d < D_DIM; d += 64) {
    float xv = xr[d];
#pragma unroll
    for (int e = 0; e < E_NUM; ++e) acc[e] += xv * Wg[e * D_DIM + d];
  }
#pragma unroll
  for (int e = 0; e < E_NUM; ++e) {
    float v = acc[e];
#pragma unroll
    for (int off = 32; off > 0; off >>= 1) v += __shfl_xor(v, off);
    acc[e] = v;
  }
  if (l == 0) {
    int i0 = 0; float m0 = acc[0];
#pragma unroll
    for (int e = 1; e < E_NUM; ++e) if (acc[e] > m0) { m0 = acc[e]; i0 = e; }
    int i1 = -1; float m1 = -INFINITY;
#pragma unroll
    for (int e = 0; e < E_NUM; ++e) if (e != i0 && acc[e] > m1) { m1 = acc[e]; i1 = e; }
    float z = expf(m1 - m0);
    float s0 = 1.f / (1.f + z);
    sc2[n * 2 + 0] = s0;
    sc2[n * 2 + 1] = 1.f - s0;
    int p0 = atomicAdd(&cnt[i0], 1);
    tok_list[i0 * N_TOK + p0] = n * 2 + 0;
    int p1 = atomicAdd(&cnt[i1], 1);
    tok_list[i1 * N_TOK + p1] = n * 2 + 1;
  }
}

__global__ void prefix_kernel(const int* __restrict__ cnt, int* __restrict__ base) {
  if (threadIdx.x == 0) {
    int s = 0;
    for (int e = 0; e < E_NUM; ++e) { base[e] = s; s += cnt[e]; }
  }
}

// ---------------- up GEMM: act[be+i][f] = silu( x[tok_i] @ W1[e] ) ----------------
// A: gathered xb rows [ce][1024] bf16; B: w1t [e][F][D] bf16 (N-major, K contig)
__global__ __launch_bounds__(256) void up_gemm(
    const u16* __restrict__ xb, const u16* __restrict__ w1t,
    const int* __restrict__ cnt, const int* __restrict__ base,
    const int* __restrict__ tok_list, u16* __restrict__ act) {
  __shared__ u16 As[128 * 32];
  __shared__ u16 Bs[128 * 32];

  const int e = blockIdx.z;
  const int ce = cnt[e];
  const int row0 = blockIdx.y * 128;
  if (row0 >= ce) return;
  const int col0 = blockIdx.x * 128;
  const int be = base[e];

  const int tid = threadIdx.x;
  const int wave = tid >> 6, lane = tid & 63;
  const int wm = wave >> 1, wn = wave & 1;
  const int lr = lane & 15, kq = lane >> 4;

  // staging geometry: segment s = wave*2+j covers LDS bytes [s*1024, s*1024+1024)
  const int rs0 = wave * 32 + (lane >> 2);  // j=0 tile-row
  const int rs1 = rs0 + 16;                 // j=1 tile-row
  const int kb = (lane & 3) * 8;            // k-element offset within BK=32

  int ga0 = row0 + rs0, ga1 = row0 + rs1;
  int e0 = (ga0 < ce) ? (tok_list[e * N_TOK + ga0] & (2 * N_TOK - 1)) : 0;
  int e1 = (ga1 < ce) ? (tok_list[e * N_TOK + ga1] & (2 * N_TOK - 1)) : 0;
  const u16* srcA0 = xb + (e0 >> 1) * D_DIM + kb;
  const u16* srcA1 = xb + (e1 >> 1) * D_DIM + kb;
  const u16* srcB0 = w1t + (size_t)(e * F_DIM + col0 + rs0) * D_DIM + kb;
  const u16* srcB1 = w1t + (size_t)(e * F_DIM + col0 + rs1) * D_DIM + kb;
  u16* ldsA0 = As + (wave * 2 + 0) * 512;
  u16* ldsA1 = As + (wave * 2 + 1) * 512;
  u16* ldsB0 = Bs + (wave * 2 + 0) * 512;
  u16* ldsB1 = Bs + (wave * 2 + 1) * 512;

  f32x4 acc[4][4];
#pragma unroll
  for (int m = 0; m < 4; ++m)
#pragma unroll
    for (int n = 0; n < 4; ++n) acc[m][n] = (f32x4){0.f, 0.f, 0.f, 0.f};

  for (int k0 = 0; k0 < D_DIM; k0 += 32) {
    gld_lds16(srcA0 + k0, ldsA0);
    gld_lds16(srcA1 + k0, ldsA1);
    gld_lds16(srcB0 + k0, ldsB0);
    gld_lds16(srcB1 + k0, ldsB1);
    __syncthreads();
    short8 a[4], b[4];
#pragma unroll
    for (int m = 0; m < 4; ++m)
      a[m] = *(const short8*)&As[(wm * 64 + m * 16 + lr) * 32 + kq * 8];
#pragma unroll
    for (int n = 0; n < 4; ++n)
      b[n] = *(const short8*)&Bs[(wn * 64 + n * 16 + lr) * 32 + kq * 8];
#pragma unroll
    for (int m = 0; m < 4; ++m)
#pragma unroll
      for (int n = 0; n < 4; ++n)
        acc[m][n] = __builtin_amdgcn_mfma_f32_16x16x32_bf16(a[m], b[n], acc[m][n], 0, 0, 0);
    __syncthreads();
  }

  // epilogue: silu -> bf16 act (C/D layout: col = lane&15, row = (lane>>4)*4 + reg)
#pragma unroll
  for (int m = 0; m < 4; ++m) {
#pragma unroll
    for (int rg = 0; rg < 4; ++rg) {
      int row = wm * 64 + m * 16 + kq * 4 + rg;
      int i = row0 + row;
      if (i < ce) {
        u16* dst = act + (size_t)(be + i) * F_DIM + col0 + wn * 64;
#pragma unroll
        for (int n = 0; n < 4; ++n) {
          float v = acc[m][n][rg];
          float s = v / (1.f + expf(-v));
          dst[n * 16 + lr] = f2bf(s);
        }
      }
    }
  }
}

// ---------------- down GEMM: out[tok] += score * ( act_row @ W2[e] ) ----------------
// A: act rows (compact, linear) [ce][4096] bf16; B: w2t [e][D][F] bf16
__global__ __launch_bounds__(256) void down_gemm(
    const u16* __restrict__ act, const u16* __restrict__ w2t,
    const int* __restrict__ cnt, const int* __restrict__ base,
    const int* __restrict__ tok_list, const float* __restrict__ sc2,
    float* __restrict__ out) {
  __shared__ u16 As[128 * 32];
  __shared__ u16 Bs[128 * 32];
  __shared__ int toks[128];

  const int e = blockIdx.z;
  const int ce = cnt[e];
  const int row0 = blockIdx.y * 128;
  if (row0 >= ce) return;
  const int col0 = blockIdx.x * 128;
  const int be = base[e];

  const int tid = threadIdx.x;
  const int wave = tid >> 6, lane = tid & 63;
  const int wm = wave >> 1, wn = wave & 1;
  const int lr = lane & 15, kq = lane >> 4;

  if (tid < 128) {
    int i = row0 + tid;
    toks[tid] = (i < ce) ? (tok_list[e * N_TOK + i] & (2 * N_TOK - 1)) : -1;
  }

  const int rs0 = wave * 32 + (lane >> 2);
  const int rs1 = rs0 + 16;
  const int kb = (lane & 3) * 8;

  int ra0 = min(be + row0 + rs0, 2 * N_TOK - 1);  // clamp: stay inside act buffer
  int ra1 = min(be + row0 + rs1, 2 * N_TOK - 1);
  const u16* srcA0 = act + (size_t)ra0 * F_DIM + kb;
  const u16* srcA1 = act + (size_t)ra1 * F_DIM + kb;
  const u16* srcB0 = w2t + (size_t)(e * D_DIM + col0 + rs0) * F_DIM + kb;
  const u16* srcB1 = w2t + (size_t)(e * D_DIM + col0 + rs1) * F_DIM + kb;
  u16* ldsA0 = As + (wave * 2 + 0) * 512;
  u16* ldsA1 = As + (wave * 2 + 1) * 512;
  u16* ldsB0 = Bs + (wave * 2 + 0) * 512;
  u16* ldsB1 = Bs + (wave * 2 + 1) * 512;

  f32x4 acc[4][4];
#pragma unroll
  for (int m = 0; m < 4; ++m)
#pragma unroll
    for (int n = 0; n < 4; ++n) acc[m][n] = (f32x4){0.f, 0.f, 0.f, 0.f};

  for (int k0 = 0; k0 < F_DIM; k0 += 32) {
    gld_lds16(srcA0 + k0, ldsA0);
    gld_lds16(srcA1 + k0, ldsA1);
    gld_lds16(srcB0 + k0, ldsB0);
    gld_lds16(srcB1 + k0, ldsB1);
    __syncthreads();
    short8 a[4], b[4];
#pragma unroll
    for (int m = 0; m < 4; ++m)
      a[m] = *(const short8*)&As[(wm * 64 + m * 16 + lr) * 32 + kq * 8];
#pragma unroll
    for (int n = 0; n < 4; ++n)
      b[n] = *(const short8*)&Bs[(wn * 64 + n * 16 + lr) * 32 + kq * 8];
#pragma unroll
    for (int m = 0; m < 4; ++m)
#pragma unroll
      for (int n = 0; n < 4; ++n)
        acc[m][n] = __builtin_amdgcn_mfma_f32_16x16x32_bf16(a[m], b[n], acc[m][n], 0, 0, 0);
    __syncthreads();
  }

  // epilogue: scatter score-scaled rows; exactly 2 commutative adds per out element
#pragma unroll
  for (int m = 0; m < 4; ++m) {
#pragma unroll
    for (int rg = 0; rg < 4; ++rg) {
      int row = wm * 64 + m * 16 + kq * 4 + rg;
      int ent = toks[row];
      if (ent >= 0) {
        int tokn = ent >> 1;
        float sc = sc2[tokn * 2 + (ent & 1)];
        float* dst = out + (size_t)tokn * D_DIM + col0 + wn * 64;
#pragma unroll
        for (int n = 0; n < 4; ++n)
          atomicAdd(&dst[n * 16 + lr], acc[m][n][rg] * sc);
      }
    }
  }
}

extern "C" void kernel_launch(void* const* d_in, const int* in_sizes, int n_in,
                              void* d_out, int out_size, void* d_ws, size_t ws_size,
                              hipStream_t stream) {
  const float* x  = (const float*)d_in[0];
  const float* Wg = (const float*)d_in[1];
  const float* W1 = (const float*)d_in[2];
  const float* W2 = (const float*)d_in[3];
  float* out = (float*)d_out;

  // workspace layout (~200.2 MiB total)
  char* ws = (char*)d_ws;
  size_t off = 0;
  u16* xb  = (u16*)(ws + off); off += (size_t)N_TOK * D_DIM * 2;          // 8 MiB
  u16* w1t = (u16*)(ws + off); off += (size_t)E_NUM * F_DIM * D_DIM * 2;  // 64 MiB
  u16* w2t = (u16*)(ws + off); off += (size_t)E_NUM * D_DIM * F_DIM * 2;  // 64 MiB
  u16* act = (u16*)(ws + off); off += (size_t)2 * N_TOK * F_DIM * 2;      // 64 MiB
  int* tok_list = (int*)(ws + off); off += (size_t)E_NUM * N_TOK * 4;     // 128 KiB
  float* sc2 = (float*)(ws + off); off += (size_t)N_TOK * 2 * 4;          // 32 KiB
  int* cnt  = (int*)(ws + off); off += 128;
  int* base = (int*)(ws + off); off += 128;

  hipMemsetAsync(d_out, 0, (size_t)out_size * 4, stream);
  hipMemsetAsync(cnt, 0, E_NUM * 4, stream);

  cvt_x_kernel<<<(N_TOK * D_DIM / 4 + 255) / 256, 256, 0, stream>>>(x, xb, N_TOK * D_DIM / 4);

  {
    dim3 blk(32, 8, 1);
    dim3 g1(F_DIM / 32, D_DIM / 32, E_NUM);  // W1 [E][D][F] -> [E][F][D]
    transpose_cvt_kernel<<<g1, blk, 0, stream>>>(W1, w1t, D_DIM, F_DIM);
    dim3 g2(D_DIM / 32, F_DIM / 32, E_NUM);  // W2 [E][F][D] -> [E][D][F]
    transpose_cvt_kernel<<<g2, blk, 0, stream>>>(W2, w2t, F_DIM, D_DIM);
  }

  gate_kernel<<<N_TOK, 64, 0, stream>>>(x, Wg, cnt, tok_list, sc2);
  prefix_kernel<<<1, 1, 0, stream>>>(cnt, base);

  {
    dim3 g(F_DIM / 128, N_TOK / 128, E_NUM);
    up_gemm<<<g, 256, 0, stream>>>(xb, w1t, cnt, base, tok_list, act);
  }
  {
    dim3 g(D_DIM / 128, N_TOK / 128, E_NUM);
    down_gemm<<<g, 256, 0, stream>>>(act, w2t, cnt, base, tok_list, sc2, out);
  }
}